// Round 17
// baseline (25.580 us; speedup 1.0000x reference)
//
#include <hip/hip_runtime.h>
#include <math.h>

// ChamferLoss: pc_src [B,3,M] f32, pc_dst [B,3,N] f32 -> scalar mean over (B,M)
// of min_n ||src_m - dst_n||.
//
// MFMA engine: d2p(n,m) = |d_n|^2 - 2 s_m . d_n as ONE K-column of
// v_mfma_f32_32x32x16_f16, split-f16 precision (per coord uh*sh, uh*sl,
// ul*sh with u=-2d; plus (wh,wl)*1; 11/16 K-slots; absmax 0.0 since R11).
//
// R16 -> R17: ~15us of R16's 23.4 was dispatch-boundary overhead (3 kernels).
// Collapse to ONE real dispatch + tiny memset, using ONLY device RMW atomics
// for cross-block communication (no threadfence — R14's 95us lesson; RMWs
// serialize at the coherent point, cross-XCD safe per m20):
//   - partial min: atomicMin(minenc) folds across ALL 1024 blocks
//   - __syncthreads before ticket drains vmcnt(0) -> this block's RMWs are
//     coherent-point-visible before its ticket RMW
//   - 16th arriver of each (b,srcgrp) group reads its 512 cols via no-op
//     RMW (atomicMin(p,UINT_MAX) returns old), sqrt+sum, fixed-point add,
//     s_waitcnt vmcnt(0), global ticket; 64th folder writes the scalar.
// Counters live in the 0xFF memset region: init -1, conditions use N-2.

#define TPB 256

constexpr int NB = 4;
constexpr int NM = 8192;
constexpr int NN = 8192;
constexpr int NPTS = NB * NM;                     // 32768
constexpr int NSEG = 16;                          // dst segments
constexpr int DSEG = NN / NSEG;                   // 512 dst per segment
constexpr int TILES = DSEG / 32;                  // 16 MFMA tiles
constexpr int NSRCG = NM / 512;                   // 16 src groups (512 cols)
constexpr int NGRP = NB * NSRCG;                  // 64 (b,srcgrp) groups

typedef _Float16 half8 __attribute__((ext_vector_type(8)));
typedef float f32x16 __attribute__((ext_vector_type(16)));

// Order-preserving float<->uint encode so unsigned atomicMin == float min.
__device__ __forceinline__ unsigned enc_f32(float f) {
    unsigned u = __float_as_uint(f);
    return (u & 0x80000000u) ? ~u : (u | 0x80000000u);
}
__device__ __forceinline__ float dec_f32(unsigned u) {
    unsigned b = (u & 0x80000000u) ? (u ^ 0x80000000u) : ~u;
    return __uint_as_float(b);
}
__device__ __forceinline__ float min3(float a, float b, float c) {
    return fminf(fminf(a, b), c);                 // -> v_min3_f32
}
__device__ __forceinline__ float tile_min(const f32x16& c, float acc) {
    float v0 = min3(c[0],  c[1],  c[2]);
    float v1 = min3(c[3],  c[4],  c[5]);
    float v2 = min3(c[6],  c[7],  c[8]);
    float v3 = min3(c[9],  c[10], c[11]);
    float v4 = min3(c[12], c[13], c[14]);
    float w0 = min3(v0, v1, c[15]);
    float w1 = min3(v2, v3, v4);
    return min3(acc, w0, w1);
}
// LDS A-frag slot for (row r, half h), 16B granules, XOR-swizzled.
__device__ __forceinline__ int aidx(int r, int h) {
    return ((r << 1) | h) ^ ((r >> 2) & 7);
}

__global__ __launch_bounds__(TPB) void fused_kernel(const float* __restrict__ src,
                                                    const float* __restrict__ dst,
                                                    unsigned* __restrict__ minenc,
                                                    unsigned* __restrict__ tg,
                                                    unsigned long long* __restrict__ sumfix,
                                                    unsigned* __restrict__ ticket,
                                                    float* __restrict__ out) {
    __shared__ uint4 alds[DSEG * 2];              // 16 KB
    __shared__ int sfold;
    __shared__ float wsum[4];

    int l  = threadIdx.x & 63;
    int wv = threadIdx.x >> 6;
    int sg = blockIdx.x & (NSEG - 1);
    int b  = (blockIdx.x >> 4) & 3;
    int srcgrp = blockIdx.x >> 6;                 // 0..15

    // ---- Phase 1a: A-frags (dst) -> LDS, 2 rows per thread ----
    const float* pd = dst + (size_t)b * 3 * NN;
#pragma unroll
    for (int rr = 0; rr < 2; ++rr) {
        int r = threadIdx.x + rr * TPB;           // row in segment
        int n = sg * DSEG + r;
        float x = pd[n], y = pd[NN + n], z = pd[2 * NN + n];
        float ux = -2.0f * x, uy = -2.0f * y, uz = -2.0f * z;
        float w = fmaf(x, x, fmaf(y, y, z * z));
        _Float16 uhx = (_Float16)ux; _Float16 ulx = (_Float16)(ux - (float)uhx);
        _Float16 uhy = (_Float16)uy; _Float16 uly = (_Float16)(uy - (float)uhy);
        _Float16 uhz = (_Float16)uz; _Float16 ulz = (_Float16)(uz - (float)uhz);
        _Float16 wh  = (_Float16)w;  _Float16 wl  = (_Float16)(w - (float)wh);
        half8 a0 = {uhx, uhx, ulx, uhy, uhy, uly, uhz, uhz};
        half8 a1 = {ulz, wh, wl, (_Float16)0.f, (_Float16)0.f,
                    (_Float16)0.f, (_Float16)0.f, (_Float16)0.f};
        alds[aidx(r, 0)] = *(uint4*)&a0;
        alds[aidx(r, 1)] = *(uint4*)&a1;
    }

    // ---- Phase 1b: B-frags (src) in regs, 4 cols per lane ----
    int mbase = (srcgrp * 4 + wv) * 128;          // wave's 128 src cols
    int lg = l & 31;
    int hi = l >> 5;                              // 0: K0-7, 1: K8-15
    const float* ps = src + (size_t)b * 3 * NM;
    half8 bf[4];
#pragma unroll
    for (int k = 0; k < 4; ++k) {
        int c = mbase + k * 32 + lg;
        float x = ps[c], y = ps[NM + c], z = ps[2 * NM + c];
        _Float16 shx = (_Float16)x; _Float16 slx = (_Float16)(x - (float)shx);
        _Float16 shy = (_Float16)y; _Float16 sly = (_Float16)(y - (float)shy);
        _Float16 shz = (_Float16)z; _Float16 slz = (_Float16)(z - (float)shz);
        half8 b0 = {shx, slx, shx, shy, sly, shy, shz, slz};
        half8 b1 = {shz, (_Float16)1.f, (_Float16)1.f, (_Float16)0.f,
                    (_Float16)0.f, (_Float16)0.f, (_Float16)0.f, (_Float16)0.f};
        bf[k] = hi ? b1 : b0;
    }
    __syncthreads();

    // ---- Phase 2: MFMA main loop, 4-way ILP ----
    const f32x16 zc = {0.f,0.f,0.f,0.f,0.f,0.f,0.f,0.f,
                       0.f,0.f,0.f,0.f,0.f,0.f,0.f,0.f};
    float acc0 = 3.4e38f, acc1 = 3.4e38f, acc2 = 3.4e38f, acc3 = 3.4e38f;
#pragma unroll 2
    for (int j = 0; j < TILES; ++j) {
        uint4 av = alds[aidx(j * 32 + lg, hi)];
        half8 af = *(half8*)&av;
        f32x16 c0 = __builtin_amdgcn_mfma_f32_32x32x16_f16(af, bf[0], zc, 0, 0, 0);
        f32x16 c1 = __builtin_amdgcn_mfma_f32_32x32x16_f16(af, bf[1], zc, 0, 0, 0);
        f32x16 c2 = __builtin_amdgcn_mfma_f32_32x32x16_f16(af, bf[2], zc, 0, 0, 0);
        f32x16 c3 = __builtin_amdgcn_mfma_f32_32x32x16_f16(af, bf[3], zc, 0, 0, 0);
        acc0 = tile_min(c0, acc0);
        acc1 = tile_min(c1, acc1);
        acc2 = tile_min(c2, acc2);
        acc3 = tile_min(c3, acc3);
    }

    acc0 = fminf(acc0, __shfl_xor(acc0, 32));     // merge lane halves
    acc1 = fminf(acc1, __shfl_xor(acc1, 32));
    acc2 = fminf(acc2, __shfl_xor(acc2, 32));
    acc3 = fminf(acc3, __shfl_xor(acc3, 32));

    // Device RMW atomics: exact min, coherent-point serialized (no fence).
    int base = b * NM + mbase;
    int lo = (l < 32);
    atomicMin(&minenc[base + (lo ? lg : 32 + lg)],      enc_f32(lo ? acc0 : acc1));
    atomicMin(&minenc[base + (lo ? 64 + lg : 96 + lg)], enc_f32(lo ? acc2 : acc3));
    __syncthreads();   // barrier drain = vmcnt(0): all block RMWs committed

    // ---- Group ticket: 16th arrival of (b,srcgrp) folds (init -1) ----
    if (threadIdx.x == 0) {
        unsigned old = atomicAdd(&tg[b * NSRCG + srcgrp], 1u);
        sfold = (old == (unsigned)(NSEG - 2));    // -1-init: 16th sees 14
    }
    __syncthreads();
    if (!sfold) return;

    // ---- Phase 3 (folder): 512 cols; coherent no-op-RMW reads; sqrt; sum --
    int gbase = b * NM + srcgrp * 512;
    float dsum = 0.0f;
#pragma unroll
    for (int cc = 0; cc < 2; ++cc) {
        int c = threadIdx.x + cc * TPB;
        int m = srcgrp * 512 + c;
        float v = dec_f32(atomicMin(&minenc[gbase + c], 0xFFFFFFFFu)); // read
        float x = ps[m], y = ps[NM + m], z = ps[2 * NM + m];
        float a2 = fmaf(x, x, fmaf(y, y, z * z));
        dsum += sqrtf(fmaxf(a2 + v, 0.0f));
    }

    for (int off = 32; off > 0; off >>= 1) dsum += __shfl_down(dsum, off);
    if (l == 0) wsum[wv] = dsum;
    __syncthreads();

    if (threadIdx.x == 0) {
        float bs = (wsum[0] + wsum[1]) + (wsum[2] + wsum[3]);
        // Fixed-point (32.32) integer accumulate: associative -> deterministic.
        unsigned long long inc = (unsigned long long)((double)bs * 4294967296.0);
        atomicAdd(sumfix, inc);
        asm volatile("s_waitcnt vmcnt(0)" ::: "memory");  // RMW committed
        unsigned tk = atomicAdd(ticket, 1u);
        if (tk == (unsigned)(NGRP - 2)) {         // -1-init: 64th sees 62
            unsigned long long tot = atomicAdd(sumfix, 0ULL) + 1ULL; // +1: -1 init
            out[0] = (float)((double)tot * (1.0 / 4294967296.0) * (1.0 / NPTS));
        }
    }
}

extern "C" void kernel_launch(void* const* d_in, const int* in_sizes, int n_in,
                              void* d_out, int out_size, void* d_ws, size_t ws_size,
                              hipStream_t stream) {
    const float* src = (const float*)d_in[0];   // [B,3,M]
    const float* dst = (const float*)d_in[1];   // [B,3,N]
    float* out = (float*)d_out;

    char* ws = (char*)d_ws;
    unsigned* minenc = (unsigned*)ws;                                // 128 KB
    unsigned* tg = (unsigned*)(ws + (size_t)NPTS * 4);               // 256 B
    unsigned long long* sumfix =
        (unsigned long long*)(ws + (size_t)NPTS * 4 + 256);          // 8 B
    unsigned* ticket = (unsigned*)(ws + (size_t)NPTS * 4 + 264);     // 4 B

    // One 0xFF fill: minenc = +inf-encoded; counters = -1; sumfix = -1.
    hipMemsetAsync(ws, 0xFF, (size_t)NPTS * 4 + 272, stream);
    fused_kernel<<<NSEG * NB * NSRCG, TPB, 0, stream>>>(src, dst, minenc, tg,
                                                        sumfix, ticket, out);
}